// Round 7
// baseline (3538.680 us; speedup 1.0000x reference)
//
#include <hip/hip_runtime.h>
#include <cstddef>

#define TT 2048   // time steps
#define BB 256    // batch
#define DD 32     // input dim
#define HH 64     // hidden
#define GG 256    // 4*H
#define RPB 16    // batch rows per recurrence block
#define NBLK (BB / RPB)   // 16 blocks

using f16   = _Float16;
using f16x4 = __attribute__((ext_vector_type(4))) _Float16;
using f16x8 = __attribute__((ext_vector_type(8))) _Float16;
using f32x4 = __attribute__((ext_vector_type(4))) float;

__device__ __forceinline__ float sigmf(float v) { return 1.0f / (1.0f + __expf(-v)); }
__device__ __forceinline__ float tanhf_(float v) { return 2.0f / (1.0f + __expf(-2.0f * v)) - 1.0f; }

// Swizzled LDS index for H buffers stored [row(16)][unit(64)] as f16.
// XOR of row into unit bits 3..5 breaks the column-read bank pathology while
// keeping 8-unit reads (16B) and 4-unit writes (8B) contiguous & aligned.
__device__ __forceinline__ int sidx(int row, int unit) {
    return row * 64 + (unit ^ ((row & 7) << 3));
}

// ---------------- pre-kernel: zx = x@W1 + b1, f16, MFMA-C-fragment layout ----------------
// zx[(((bb>>4)*TT + t)*16 + m)*256 + lg*64 + (bb&15)*4 + rs] = z[bb][t][16m + lg*4 + rs]
__global__ __launch_bounds__(256)
void zx_pre(const float* __restrict__ x, const float* __restrict__ W1,
            const float* __restrict__ b1, f16* __restrict__ zx)
{
    const int bb = blockIdx.x;       // batch row (fast dim: 16 bb's share zx region)
    const int tb = blockIdx.y;       // t-tile of 8
    const int zr = threadIdx.x;      // z-row (gate-major column of W1), 0..255
    __shared__ float xs[8][DD];

    const float* xb = x + ((size_t)bb * TT + (size_t)tb * 8) * DD;
    xs[zr >> 5][zr & 31] = xb[zr];
    __syncthreads();

    float wcol[DD];
    #pragma unroll
    for (int d = 0; d < DD; ++d) wcol[d] = W1[d * GG + zr];
    const float bias = b1[zr];

    const int m = zr >> 4, lg = (zr >> 2) & 3, rs = zr & 3;
    f16* base = zx + ((((size_t)(bb >> 4)) * TT + (size_t)tb * 8) * 16 + m) * 256
                   + lg * 64 + (bb & 15) * 4 + rs;
    #pragma unroll
    for (int r8 = 0; r8 < 8; ++r8) {
        float z0 = bias, z1 = 0.f, z2 = 0.f, z3 = 0.f;
        #pragma unroll
        for (int d = 0; d < DD; d += 4) {
            z0 += xs[r8][d+0] * wcol[d+0];
            z1 += xs[r8][d+1] * wcol[d+1];
            z2 += xs[r8][d+2] * wcol[d+2];
            z3 += xs[r8][d+3] * wcol[d+3];
        }
        base[(size_t)r8 * 4096] = (f16)((z0 + z1) + (z2 + z3));
    }
}

// ---------------- recurrence: 16 rows/block via MFMA (fp16 in, fp32 acc) ----------------
// 8 waves. Waves 0-3: layer-1 (one step ahead), wave w owns D-tiles {w,w+4,w+8,w+12}
// = all 4 gates (gp) of units 16w + lg*4 + r. Waves 4-7: layer-2 + projection.
// Lane l: batch row l&15, 4 units in regs r=0..3, ALL gates in-thread -> cell
// update has zero shuffles. H crosses waves via swizzled LDS f16; 1 barrier/step.
__global__ __launch_bounds__(512, 2)
void dlstm_rec(const f16* __restrict__ zx,
               const float* __restrict__ U1,
               const float* __restrict__ W2, const float* __restrict__ U2,
               const float* __restrict__ b2,
               const float* __restrict__ Wd, const float* __restrict__ bd,
               float* __restrict__ out)
{
    const int tid = threadIdx.x, blk = blockIdx.x;
    const int wid = tid >> 6, l = tid & 63;
    const int lg = l >> 4, lr = l & 15;
    const int w = wid & 3;

    __shared__ __align__(16) f16 Hs1[2][RPB * 64];
    __shared__ __align__(16) f16 Hs2[2][RPB * 64];
    __shared__ float PP[2][4][16];

    for (int i = tid; i < RPB * 64; i += 512) {
        Hs1[0][i] = (f16)0.f; Hs1[1][i] = (f16)0.f;
        Hs2[0][i] = (f16)0.f; Hs2[1][i] = (f16)0.f;
    }
    if (tid < 128) ((float*)PP)[tid] = 0.f;
    __syncthreads();

    if (wid < 4) {
        // ---------------- layer-1 engine: computes h1(n) at iter n ----------------
        f16x8 a1[4][2];   // A-frags of U1^T: tile m=w+4gp, two K=32 halves
        #pragma unroll
        for (int gp = 0; gp < 4; ++gp) {
            const int col = 16 * (w + 4 * gp) + lr;
            #pragma unroll
            for (int k = 0; k < 2; ++k) {
                const int kr = 32 * k + lg * 8;
                #pragma unroll
                for (int j = 0; j < 8; ++j) a1[gp][k][j] = (f16)U1[(kr + j) * GG + col];
            }
        }
        const float bd0 = bd[0];
        const f16* zxb = zx + (size_t)blk * TT * 4096 + (size_t)l * 4;
        f16x4 zc[4], zn[4];
        #pragma unroll
        for (int gp = 0; gp < 4; ++gp) zc[gp] = *(const f16x4*)(zxb + (w + 4 * gp) * 256);
        float c1[4] = {0.f, 0.f, 0.f, 0.f};

        for (int n = 0; n < TT + 2; ++n) {
            const int p = n & 1;
            if (n < TT) {
                const size_t tn = (n + 1 < TT) ? (size_t)(n + 1) : (size_t)n;
                #pragma unroll
                for (int gp = 0; gp < 4; ++gp)
                    zn[gp] = *(const f16x4*)(zxb + tn * 4096 + (w + 4 * gp) * 256);

                bf16x8_dummy:;
                f16x8 hb[2];
                #pragma unroll
                for (int k = 0; k < 2; ++k)
                    hb[k] = *(const f16x8*)&Hs1[p][sidx(lr, 32 * k + lg * 8)];

                f32x4 acc[4];
                #pragma unroll
                for (int gp = 0; gp < 4; ++gp) {
                    f32x4 ci;
                    #pragma unroll
                    for (int r = 0; r < 4; ++r) ci[r] = (float)zc[gp][r];
                    acc[gp] = __builtin_amdgcn_mfma_f32_16x16x32_f16(a1[gp][0], hb[0], ci, 0, 0, 0);
                    acc[gp] = __builtin_amdgcn_mfma_f32_16x16x32_f16(a1[gp][1], hb[1], acc[gp], 0, 0, 0);
                }
                f16x4 hp;
                #pragma unroll
                for (int r = 0; r < 4; ++r) {
                    float gi = sigmf(acc[0][r]);
                    float gf = sigmf(acc[1][r]);
                    float gc = tanhf_(acc[2][r]);
                    float go = sigmf(acc[3][r]);
                    c1[r] = gf * c1[r] + gi * gc;
                    hp[r] = (f16)(go * tanhf_(c1[r]));
                }
                *(f16x4*)&Hs1[p ^ 1][sidx(lr, 16 * w + lg * 4)] = hp;
                #pragma unroll
                for (int gp = 0; gp < 4; ++gp) zc[gp] = zn[gp];
            }
            // out(n-2): partials written by L2 at iter n-1
            if (wid == 0 && l < 16 && n >= 2) {
                float s = PP[p][0][l] + PP[p][1][l] + PP[p][2][l] + PP[p][3][l];
                out[(size_t)(blk * RPB + l) * TT + (n - 2)] = sigmf(s + bd0);
            }
            __syncthreads();
        }
    } else {
        // ---------------- layer-2 engine: computes h2(n-1) at iter n ----------------
        f16x8 aw[4][2], au[4][2];
        f32x4 ci[4];
        float wd[4];
        #pragma unroll
        for (int gp = 0; gp < 4; ++gp) {
            const int col = 16 * (w + 4 * gp) + lr;
            #pragma unroll
            for (int k = 0; k < 2; ++k) {
                const int kr = 32 * k + lg * 8;
                #pragma unroll
                for (int j = 0; j < 8; ++j) {
                    aw[gp][k][j] = (f16)W2[(kr + j) * GG + col];
                    au[gp][k][j] = (f16)U2[(kr + j) * GG + col];
                }
            }
            #pragma unroll
            for (int r = 0; r < 4; ++r) ci[gp][r] = b2[64 * gp + 16 * w + lg * 4 + r];
        }
        #pragma unroll
        for (int r = 0; r < 4; ++r) wd[r] = Wd[16 * w + lg * 4 + r];
        float c2[4] = {0.f, 0.f, 0.f, 0.f};

        for (int n = 0; n < TT + 2; ++n) {
            const int p = n & 1;
            if (n >= 1 && n <= TT) {
                f16x8 hb1[2], hb2[2];
                #pragma unroll
                for (int k = 0; k < 2; ++k) {
                    hb1[k] = *(const f16x8*)&Hs1[p][sidx(lr, 32 * k + lg * 8)];
                    hb2[k] = *(const f16x8*)&Hs2[p][sidx(lr, 32 * k + lg * 8)];
                }
                f32x4 acc[4];
                #pragma unroll
                for (int gp = 0; gp < 4; ++gp) {
                    acc[gp] = __builtin_amdgcn_mfma_f32_16x16x32_f16(aw[gp][0], hb1[0], ci[gp], 0, 0, 0);
                    acc[gp] = __builtin_amdgcn_mfma_f32_16x16x32_f16(aw[gp][1], hb1[1], acc[gp], 0, 0, 0);
                    acc[gp] = __builtin_amdgcn_mfma_f32_16x16x32_f16(au[gp][0], hb2[0], acc[gp], 0, 0, 0);
                    acc[gp] = __builtin_amdgcn_mfma_f32_16x16x32_f16(au[gp][1], hb2[1], acc[gp], 0, 0, 0);
                }
                f16x4 hp;
                float pv = 0.f;
                #pragma unroll
                for (int r = 0; r < 4; ++r) {
                    float gi = sigmf(acc[0][r]);
                    float gf = sigmf(acc[1][r]);
                    float gc = tanhf_(acc[2][r]);
                    float go = sigmf(acc[3][r]);
                    c2[r] = gf * c2[r] + gi * gc;
                    float h = go * tanhf_(c2[r]);
                    hp[r] = (f16)h;
                    pv += h * wd[r];
                }
                *(f16x4*)&Hs2[p ^ 1][sidx(lr, 16 * w + lg * 4)] = hp;
                // projection partial: sum over this wave's 16 units (lg groups)
                pv += __shfl_xor(pv, 16, 64);
                pv += __shfl_xor(pv, 32, 64);
                if (l < 16) PP[p ^ 1][w][l] = pv;
            }
            __syncthreads();
        }
    }
}

// ---------------- fallback (R2 structure, fp32-exact) if ws too small ----------------
__global__ __launch_bounds__(512, 2)
void dlstm_fallback(const float* __restrict__ x,
                    const float* __restrict__ W1, const float* __restrict__ U1,
                    const float* __restrict__ b1,
                    const float* __restrict__ W2, const float* __restrict__ U2,
                    const float* __restrict__ b2,
                    const float* __restrict__ Wd, const float* __restrict__ bd,
                    float* __restrict__ out)
{
    const int tid = threadIdx.x;
    const int b   = blockIdx.x;
    const int wid = tid >> 6;
    const int l   = tid & 63;
    const int g   = l >> 4;
    const int uo  = l & 15;

    __shared__ __align__(16) float h1b[2][HH];
    __shared__ __align__(16) float h2b[2][HH];
    __shared__ float pbuf[2][4];

    if (tid < HH) { h1b[0][tid] = 0.f; h1b[1][tid] = 0.f; h2b[0][tid] = 0.f; h2b[1][tid] = 0.f; }
    if (tid < 8) pbuf[tid >> 2][tid & 3] = 0.f;
    __syncthreads();

    if (wid < 4) {
        const int u   = (wid << 4) + uo;
        const int col = (g << 6) + u;
        float w1c[DD], u1c[HH];
        #pragma unroll
        for (int d = 0; d < DD; ++d) w1c[d] = W1[d * GG + col];
        #pragma unroll
        for (int j = 0; j < HH; ++j) u1c[j] = U1[j * GG + col];
        const float b1k = b1[col], bd0 = bd[0];
        float c1 = 0.f;
        const float* xrow = x + (size_t)b * (TT * DD);
        float4 xv[8];
        #pragma unroll
        for (int q = 0; q < 8; ++q) xv[q] = ((const float4*)xrow)[q];

        for (int n = 0; n < TT + 2; ++n) {
            const int p = n & 1;
            if (n < TT) {
                const float4* xnp = (const float4*)(xrow + (size_t)((n + 1 < TT) ? n + 1 : n) * DD);
                float4 xn[8];
                #pragma unroll
                for (int q = 0; q < 8; ++q) xn[q] = xnp[q];
                float a0 = b1k, a1 = 0.f, a2 = 0.f, a3 = 0.f;
                #pragma unroll
                for (int q = 0; q < 8; ++q) {
                    a0 += xv[q].x * w1c[4*q+0]; a1 += xv[q].y * w1c[4*q+1];
                    a2 += xv[q].z * w1c[4*q+2]; a3 += xv[q].w * w1c[4*q+3];
                }
                const float4* hp = (const float4*)h1b[p];
                #pragma unroll
                for (int q = 0; q < 16; ++q) {
                    float4 hv = hp[q];
                    a0 += hv.x * u1c[4*q+0]; a1 += hv.y * u1c[4*q+1];
                    a2 += hv.z * u1c[4*q+2]; a3 += hv.w * u1c[4*q+3];
                }
                float z = (a0 + a1) + (a2 + a3);
                float a = (g == 2) ? tanhf_(z) : sigmf(z);
                float p16 = __shfl_xor(a, 16, 64);
                float p32 = __shfl_xor(a, 32, 64);
                float p48 = __shfl_xor(p16, 32, 64);
                float gi = (g==0) ? a   : (g==1) ? p16 : (g==2) ? p32 : p48;
                float gf = (g==0) ? p16 : (g==1) ? a   : (g==2) ? p48 : p32;
                float gc = (g==0) ? p32 : (g==1) ? p48 : (g==2) ? a   : p16;
                float go = (g==0) ? p48 : (g==1) ? p32 : (g==2) ? p16 : a;
                c1 = gf * c1 + gi * gc;
                float h = go * tanhf_(c1);
                if (g == 0) h1b[p ^ 1][u] = h;
                #pragma unroll
                for (int q = 0; q < 8; ++q) xv[q] = xn[q];
            }
            if (tid == 0 && n >= 2) {
                float s = pbuf[p][0] + pbuf[p][1] + pbuf[p][2] + pbuf[p][3];
                out[(size_t)b * TT + (n - 2)] = sigmf(s + bd0);
            }
            __syncthreads();
        }
    } else {
        const int w2i = wid - 4;
        const int u   = (w2i << 4) + uo;
        const int col = (g << 6) + u;
        float w2c[HH], u2c[HH];
        #pragma unroll
        for (int j = 0; j < HH; ++j) w2c[j] = W2[j * GG + col];
        #pragma unroll
        for (int j = 0; j < HH; ++j) u2c[j] = U2[j * GG + col];
        const float b2k = b2[col];
        const float wdk = Wd[u];
        float c2 = 0.f;

        for (int n = 0; n < TT + 2; ++n) {
            const int p = n & 1;
            if (n >= 1 && n <= TT) {
                float d0 = b2k, d1 = 0.f, d2 = 0.f, d3 = 0.f;
                const float4* h1p = (const float4*)h1b[p];
                const float4* h2p = (const float4*)h2b[p];
                #pragma unroll
                for (int q = 0; q < 16; ++q) {
                    float4 hv = h1p[q];
                    d0 += hv.x * w2c[4*q+0]; d1 += hv.y * w2c[4*q+1];
                    d2 += hv.z * w2c[4*q+2]; d3 += hv.w * w2c[4*q+3];
                }
                #pragma unroll
                for (int q = 0; q < 16; ++q) {
                    float4 hv = h2p[q];
                    d0 += hv.x * u2c[4*q+0]; d1 += hv.y * u2c[4*q+1];
                    d2 += hv.z * u2c[4*q+2]; d3 += hv.w * u2c[4*q+3];
                }
                float z = (d0 + d1) + (d2 + d3);
                float a = (g == 2) ? tanhf_(z) : sigmf(z);
                float p16 = __shfl_xor(a, 16, 64);
                float p32 = __shfl_xor(a, 32, 64);
                float p48 = __shfl_xor(p16, 32, 64);
                float gi = (g==0) ? a   : (g==1) ? p16 : (g==2) ? p32 : p48;
                float gf = (g==0) ? p16 : (g==1) ? a   : (g==2) ? p48 : p32;
                float gc = (g==0) ? p32 : (g==1) ? p48 : (g==2) ? a   : p16;
                float go = (g==0) ? p48 : (g==1) ? p32 : (g==2) ? p16 : a;
                c2 = gf * c2 + gi * gc;
                float h = go * tanhf_(c2);
                if (g == 0) h2b[p ^ 1][u] = h;
                float v = (g == 0) ? h * wdk : 0.f;
                v += __shfl_xor(v, 1, 64);
                v += __shfl_xor(v, 2, 64);
                v += __shfl_xor(v, 4, 64);
                v += __shfl_xor(v, 8, 64);
                if (l == 0) pbuf[p ^ 1][w2i] = v;
            }
            __syncthreads();
        }
    }
}

extern "C" void kernel_launch(void* const* d_in, const int* in_sizes, int n_in,
                              void* d_out, int out_size, void* d_ws, size_t ws_size,
                              hipStream_t stream) {
    const float* x  = (const float*)d_in[0];
    const float* W1 = (const float*)d_in[1];
    const float* U1 = (const float*)d_in[2];
    const float* b1 = (const float*)d_in[3];
    const float* W2 = (const float*)d_in[4];
    const float* U2 = (const float*)d_in[5];
    const float* b2 = (const float*)d_in[6];
    const float* Wd = (const float*)d_in[7];
    const float* bd = (const float*)d_in[8];
    float* out = (float*)d_out;

    const size_t need_f16 = (size_t)NBLK * TT * 16 * 256 * sizeof(f16);  // 268 MB

    if (ws_size >= need_f16) {
        f16* zxw = (f16*)d_ws;
        zx_pre<<<dim3(BB, TT / 8), dim3(256), 0, stream>>>(x, W1, b1, zxw);
        dlstm_rec<<<dim3(NBLK), dim3(512), 0, stream>>>(zxw, U1, W2, U2, b2, Wd, bd, out);
    } else {
        dlstm_fallback<<<dim3(BB), dim3(512), 0, stream>>>(x, W1, U1, b1, W2, U2, b2, Wd, bd, out);
    }
}

// Round 8
// 1921.340 us; speedup vs baseline: 1.8418x; 1.8418x over previous
//
#include <hip/hip_runtime.h>
#include <hip/hip_fp16.h>
#include <cstddef>

#define TT 2048   // time steps
#define BB 256    // batch
#define DD 32     // input dim
#define HH 64     // hidden
#define GG 256    // 4*H

__device__ __forceinline__ float sigmf(float v)  { return 1.0f / (1.0f + __expf(-v)); }
__device__ __forceinline__ float tanhf_(float v) { return 2.0f / (1.0f + __expf(-2.0f * v)) - 1.0f; }

// One block per batch row; 512 threads = 8 waves.
// Waves 0-3: layer-1 engine (one step ahead). Waves 4-7: layer-2 + projection.
// Thread map: unit u = wid*16 + (l&15), K-quarter kq = l>>4. Each thread owns all
// 4 gates of its unit over its K-chunk, with MACs done as v_pk_fma_f16 (2/instr).
// Partial combine across kq + gate all-gather = 6 shfl_xor; cell update valid in
// kq0 lanes only (no select chains). One barrier per step.
__global__ __launch_bounds__(512, 2)
void dlstm_kernel(const float* __restrict__ x,
                  const float* __restrict__ W1, const float* __restrict__ U1,
                  const float* __restrict__ b1,
                  const float* __restrict__ W2, const float* __restrict__ U2,
                  const float* __restrict__ b2,
                  const float* __restrict__ Wd, const float* __restrict__ bd,
                  float* __restrict__ out)
{
    const int tid = threadIdx.x, b = blockIdx.x;
    const int wid = tid >> 6, l = tid & 63;
    const int kq = l >> 4, ul = l & 15;

    __shared__ __align__(16) __half h1b[2][HH];
    __shared__ __align__(16) __half h2b[2][HH];
    __shared__ float pbuf[2][4];

    if (tid < HH) {
        h1b[0][tid] = __float2half(0.f); h1b[1][tid] = __float2half(0.f);
        h2b[0][tid] = __float2half(0.f); h2b[1][tid] = __float2half(0.f);
    }
    if (tid < 8) pbuf[tid >> 2][tid & 3] = 0.f;
    __syncthreads();

    if (wid < 4) {
        // ================= layer-1 engine: computes h1(n) at iter n =================
        const int u = (wid << 4) + ul;
        // U1 chunk: gate gp, rows kq*16..+16, col gp*64+u -> 8 half2 per gate
        __half2 u1p[4][8];
        #pragma unroll
        for (int gp = 0; gp < 4; ++gp)
            #pragma unroll
            for (int j = 0; j < 8; ++j)
                u1p[gp][j] = __floats2half2_rn(U1[(kq*16 + 2*j    ) * GG + gp*HH + u],
                                               U1[(kq*16 + 2*j + 1) * GG + gp*HH + u]);
        // W1 chunk: rows kq*8..+8 -> 4 half2 per gate
        __half2 w1p[4][4];
        #pragma unroll
        for (int gp = 0; gp < 4; ++gp)
            #pragma unroll
            for (int j = 0; j < 4; ++j)
                w1p[gp][j] = __floats2half2_rn(W1[(kq*8 + 2*j    ) * GG + gp*HH + u],
                                               W1[(kq*8 + 2*j + 1) * GG + gp*HH + u]);
        const float b1k = b1[kq * HH + u];
        const float bd0 = bd[0];
        float c1 = 0.f;

        const float* xr = x + (size_t)b * TT * DD + kq * 8;   // my 8 x-rows
        float4 xa = *(const float4*)(xr);
        float4 xb = *(const float4*)(xr + 4);

        for (int n = 0; n < TT + 2; ++n) {
            const int p = n & 1;
            if (n < TT) {
                // prefetch x(n+1): in flight under the whole step
                const size_t tn = (n + 1 < TT) ? (size_t)(n + 1) : (size_t)n;
                float4 na = *(const float4*)(xr + tn * DD);
                float4 nb = *(const float4*)(xr + tn * DD + 4);

                __half2 xx[4];
                xx[0] = __floats2half2_rn(xa.x, xa.y);
                xx[1] = __floats2half2_rn(xa.z, xa.w);
                xx[2] = __floats2half2_rn(xb.x, xb.y);
                xx[3] = __floats2half2_rn(xb.z, xb.w);

                const __half2* hp = (const __half2*)&h1b[p][kq * 16];
                __half2 hh[8];
                #pragma unroll
                for (int j = 0; j < 8; ++j) hh[j] = hp[j];

                float ag[4];
                #pragma unroll
                for (int gp = 0; gp < 4; ++gp) {
                    __half2 s = __float2half2_rn(0.f);
                    #pragma unroll
                    for (int j = 0; j < 8; ++j) s = __hfma2(u1p[gp][j], hh[j], s);
                    #pragma unroll
                    for (int j = 0; j < 4; ++j) s = __hfma2(w1p[gp][j], xx[j], s);
                    ag[gp] = __low2float(s) + __high2float(s);
                }
                // combine across kq: lane ends with z-total of gate kq (R5-verified)
                float t1 = (kq & 1) ? ag[0] : ag[1];
                float t2 = (kq & 1) ? ag[2] : ag[3];
                float r1 = __shfl_xor(t1, 16, 64);
                float r2 = __shfl_xor(t2, 16, 64);
                float m1 = (kq & 1) ? ag[1] : ag[0];
                float m2 = (kq & 1) ? ag[3] : ag[2];
                float s1 = m1 + r1, s2 = m2 + r2;
                float t3 = (kq < 2) ? s2 : s1;
                float r3 = __shfl_xor(t3, 32, 64);
                float mine = (kq < 2) ? s1 : s2;
                float z = mine + r3 + b1k;

                float a = (kq == 2) ? tanhf_(z) : sigmf(z);
                // all-gather: valid gate roles land in kq0 lanes (others garbage, unused)
                float g16 = __shfl_xor(a, 16, 64);
                float g32 = __shfl_xor(a, 32, 64);
                float g48 = __shfl_xor(g16, 32, 64);
                c1 = g16 * c1 + a * g32;         // kq0: i=a, f=g16, c~=g32, o=g48
                float h = g48 * tanhf_(c1);
                if (kq == 0) h1b[p ^ 1][u] = __float2half(h);

                xa = na; xb = nb;
            }
            // out(n-2): partials written by L2 at iter n-1
            if (tid == 0 && n >= 2) {
                float s = pbuf[p][0] + pbuf[p][1] + pbuf[p][2] + pbuf[p][3];
                out[(size_t)b * TT + (n - 2)] = sigmf(s + bd0);
            }
            __syncthreads();
        }
    } else {
        // ================= layer-2 engine: computes h2(n-1) at iter n =================
        const int w2i = wid - 4;
        const int u = (w2i << 4) + ul;
        __half2 w2p[4][8], u2p[4][8];
        #pragma unroll
        for (int gp = 0; gp < 4; ++gp)
            #pragma unroll
            for (int j = 0; j < 8; ++j) {
                w2p[gp][j] = __floats2half2_rn(W2[(kq*16 + 2*j    ) * GG + gp*HH + u],
                                               W2[(kq*16 + 2*j + 1) * GG + gp*HH + u]);
                u2p[gp][j] = __floats2half2_rn(U2[(kq*16 + 2*j    ) * GG + gp*HH + u],
                                               U2[(kq*16 + 2*j + 1) * GG + gp*HH + u]);
            }
        const float b2k = b2[kq * HH + u];
        const float wdu = Wd[u];
        float c2 = 0.f;

        for (int n = 0; n < TT + 2; ++n) {
            const int p = n & 1;
            if (n >= 1 && n <= TT) {
                const __half2* h1p = (const __half2*)&h1b[p][kq * 16];
                const __half2* h2p = (const __half2*)&h2b[p][kq * 16];
                __half2 hh1[8], hh2[8];
                #pragma unroll
                for (int j = 0; j < 8; ++j) { hh1[j] = h1p[j]; hh2[j] = h2p[j]; }

                float ag[4];
                #pragma unroll
                for (int gp = 0; gp < 4; ++gp) {
                    __half2 s = __float2half2_rn(0.f);
                    #pragma unroll
                    for (int j = 0; j < 8; ++j) s = __hfma2(w2p[gp][j], hh1[j], s);
                    #pragma unroll
                    for (int j = 0; j < 8; ++j) s = __hfma2(u2p[gp][j], hh2[j], s);
                    ag[gp] = __low2float(s) + __high2float(s);
                }
                float t1 = (kq & 1) ? ag[0] : ag[1];
                float t2 = (kq & 1) ? ag[2] : ag[3];
                float r1 = __shfl_xor(t1, 16, 64);
                float r2 = __shfl_xor(t2, 16, 64);
                float m1 = (kq & 1) ? ag[1] : ag[0];
                float m2 = (kq & 1) ? ag[3] : ag[2];
                float s1 = m1 + r1, s2 = m2 + r2;
                float t3 = (kq < 2) ? s2 : s1;
                float r3 = __shfl_xor(t3, 32, 64);
                float mine = (kq < 2) ? s1 : s2;
                float z = mine + r3 + b2k;

                float a = (kq == 2) ? tanhf_(z) : sigmf(z);
                float g16 = __shfl_xor(a, 16, 64);
                float g32 = __shfl_xor(a, 32, 64);
                float g48 = __shfl_xor(g16, 32, 64);
                c2 = g16 * c2 + a * g32;         // kq0 roles
                float h = g48 * tanhf_(c2);
                if (kq == 0) h2b[p ^ 1][u] = __float2half(h);

                // projection partial: only kq0 lanes contribute real h
                float v = (kq == 0) ? h * wdu : 0.f;
                v += __shfl_xor(v, 1, 64);
                v += __shfl_xor(v, 2, 64);
                v += __shfl_xor(v, 4, 64);
                v += __shfl_xor(v, 8, 64);
                if (l == 0) pbuf[p ^ 1][w2i] = v;
            }
            __syncthreads();
        }
    }
}

extern "C" void kernel_launch(void* const* d_in, const int* in_sizes, int n_in,
                              void* d_out, int out_size, void* d_ws, size_t ws_size,
                              hipStream_t stream) {
    const float* x  = (const float*)d_in[0];
    const float* W1 = (const float*)d_in[1];
    const float* U1 = (const float*)d_in[2];
    const float* b1 = (const float*)d_in[3];
    const float* W2 = (const float*)d_in[4];
    const float* U2 = (const float*)d_in[5];
    const float* b2 = (const float*)d_in[6];
    const float* Wd = (const float*)d_in[7];
    const float* bd = (const float*)d_in[8];
    float* out = (float*)d_out;

    dlstm_kernel<<<dim3(BB), dim3(512), 0, stream>>>(
        x, W1, U1, b1, W2, U2, b2, Wd, bd, out);
}